// Round 4
// baseline (8855.538 us; speedup 1.0000x reference)
//
#include <hip/hip_runtime.h>

#define Tn 512
#define In 40
#define Hn 256
#define Kn 4
#define On 16
#define RES 12              // resident rec j2-chunks per out-col (j < 96)
#define NJ2 32              // total rec j2-chunks (256/8)
#define NSB 10              // streamed batches (j2 pairs): j2 = 12..31

typedef _Float16 half8  __attribute__((ext_vector_type(8)));
typedef _Float16 half2v __attribute__((ext_vector_type(2)));

union UH { uint4 u; half8 h; half2v h2[4]; };

static __device__ __forceinline__ float tanh_fast(float x) {
    float e = __expf(2.f * x);
    return 1.f - 2.f * __builtin_amdgcn_rcpf(e + 1.f);
}

// Pack weights to fp16, chunked for per-lane uint4 loads:
//   WPr[(j2*1024 + me)*8 + j] = W_rec[me][j2*8+j],  j2 = 0..31, me = 0..1023
//   WPi[(i2*1024 + me)*8 + j] = W_in [me][i2*8+j],  i2 = 0..4   (40 = 5*8)
__global__ void pack_w(const float* __restrict__ Wr, const float* __restrict__ Wi,
                       _Float16* __restrict__ WPr, _Float16* __restrict__ WPi) {
    const int me = threadIdx.x;           // 0..1023
    const int c  = blockIdx.x;            // 0..36
    if (c < NJ2) {
#pragma unroll
        for (int j = 0; j < 8; j++)
            WPr[((size_t)c * 1024 + me) * 8 + j] = (_Float16)Wr[(size_t)me * Hn + c * 8 + j];
    } else {
        const int i2 = c - NJ2;
#pragma unroll
        for (int j = 0; j < 8; j++)
            WPi[((size_t)i2 * 1024 + me) * 8 + j] = (_Float16)Wi[(size_t)me * In + i2 * 8 + j];
    }
}

// 256 blocks x 512 threads (8 waves). Thread tid owns out-cols me0=tid,
// me1=tid+512 (same hp=tid&255, compartments k0=tid>>8 and k0+2) for 4 rows.
// Weights j<96 live in VGPRs; j in [96,256) streamed from L2 (3-deep batches).
// h and x are read from LDS at wave-uniform addresses (hardware broadcast).
__global__ __launch_bounds__(512, 2) void diru_reg(
    const float* __restrict__ x,
    const _Float16* __restrict__ WPr,
    const _Float16* __restrict__ WPi,
    const float* __restrict__ b_in, const float* __restrict__ b_rec,
    const float* __restrict__ W_gate, const float* __restrict__ b_gate,
    const float* __restrict__ W_fc, const float* __restrict__ b_fc,
    float* __restrict__ out)
{
    const int tid  = threadIdx.x;
    const int lane = tid & 63, wav = tid >> 6;
    const int me0  = tid, me1 = tid + 512;
    const int k0   = tid >> 8;            // 0 or 1 (me1 -> k0+2)
    const int hp   = tid & 255;
    const int b0   = blockIdx.x * 4;

    __shared__ _Float16 hh[4][Hn];        // carried h, fp16 (rows 512B)
    __shared__ _Float16 xs[4][In];        // x_t fp16 (rows 80B, 16B-aligned)
    __shared__ float    red[8][16];       // per-wave gate partials [wav][r*4+kg]
    __shared__ float    hpart[2][4][Hn];  // h_new partials by k0-half

    const uint4* __restrict__ WR4 = (const uint4*)WPr;
    const uint4* __restrict__ WI4 = (const uint4*)WPi;

    // ---- resident weights ----
    UH wr0[RES], wr1[RES];
#pragma unroll
    for (int j2 = 0; j2 < RES; j2++) {
        wr0[j2].u = WR4[(size_t)j2 * 1024 + me0];
        wr1[j2].u = WR4[(size_t)j2 * 1024 + me1];
    }
    UH wi0[5], wi1[5];
#pragma unroll
    for (int i2 = 0; i2 < 5; i2++) {
        wi0[i2].u = WI4[(size_t)i2 * 1024 + me0];
        wi1[i2].u = WI4[(size_t)i2 * 1024 + me1];
    }
    float Wg0[4], Wg1[4], bg[4];
#pragma unroll
    for (int kg = 0; kg < 4; kg++) {
        Wg0[kg] = W_gate[kg * 1024 + me0];
        Wg1[kg] = W_gate[kg * 1024 + me1];
        bg[kg]  = b_gate[kg];
    }
    const float bias0 = b_in[me0] + b_rec[me0];
    const float bias1 = b_in[me1] + b_rec[me1];

    // ---- init LDS: zero h, stage x(t=0) ----
    for (int i = tid; i < 4 * Hn; i += 512) ((_Float16*)hh)[i] = (_Float16)0.f;
    const int  xv_id  = tid - 256;                       // threads 256..415 stage x
    const bool is_x   = (xv_id >= 0) && (xv_id < 4 * In);
    const int  xr     = is_x ? (xv_id / In) : 0;
    const int  xi     = is_x ? (xv_id - xr * In) : 0;
    const float* xp   = x + ((size_t)(b0 + xr) * Tn) * In + xi;
    if (is_x) xs[xr][xi] = (_Float16)xp[0];

    // stream base pointers (j2 = RES..31)
    const uint4* sa0 = WR4 + (size_t)RES * 1024 + me0;
    const uint4* sa1 = WR4 + (size_t)RES * 1024 + me1;

    for (int t = 0; t < Tn; t++) {
        // prefetch next x early (lands during compute)
        float xpre = 0.f;
        if (is_x && (t + 1 < Tn)) xpre = xp[(size_t)(t + 1) * In];

        __syncthreads();   // hh(t), xs(t) ready

        float a0[4], a1[4];
#pragma unroll
        for (int r = 0; r < 4; r++) { a0[r] = bias0; a1[r] = bias1; }

        // ---- input projection (broadcast xs reads, resident weights) ----
#pragma unroll
        for (int i2 = 0; i2 < 5; i2++) {
#pragma unroll
            for (int r = 0; r < 4; r++) {
                UH xv; xv.h = *(const half8*)&xs[r][i2 * 8];
#pragma unroll
                for (int p = 0; p < 4; p++) {
                    a0[r] = __builtin_amdgcn_fdot2(xv.h2[p], wi0[i2].h2[p], a0[r], false);
                    a1[r] = __builtin_amdgcn_fdot2(xv.h2[p], wi1[i2].h2[p], a1[r], false);
                }
            }
        }

        // ---- recurrent, resident half (j < 96), interleave stream issue ----
        UH sb[3][2][2];   // [slot][j2-of-pair][out]
#define ISSUE(slot, b) { \
            sb[slot][0][0].u = sa0[(size_t)(2*(b)) * 1024];     \
            sb[slot][1][0].u = sa0[(size_t)(2*(b)+1) * 1024];   \
            sb[slot][0][1].u = sa1[(size_t)(2*(b)) * 1024];     \
            sb[slot][1][1].u = sa1[(size_t)(2*(b)+1) * 1024]; }

#pragma unroll
        for (int j2 = 0; j2 < RES; j2++) {
            if (j2 == 4)  ISSUE(0, 0);
            if (j2 == 8)  ISSUE(1, 1);
            if (j2 == 11) ISSUE(2, 2);
#pragma unroll
            for (int r = 0; r < 4; r++) {
                UH hv; hv.h = *(const half8*)&hh[r][j2 * 8];
#pragma unroll
                for (int p = 0; p < 4; p++) {
                    a0[r] = __builtin_amdgcn_fdot2(hv.h2[p], wr0[j2].h2[p], a0[r], false);
                    a1[r] = __builtin_amdgcn_fdot2(hv.h2[p], wr1[j2].h2[p], a1[r], false);
                }
            }
        }

        // ---- recurrent, streamed half (j in [96,256)), 3-deep pipeline ----
#pragma unroll
        for (int b = 0; b < NSB; b++) {
            const int slot = b % 3;
#pragma unroll
            for (int jj = 0; jj < 2; jj++) {
                const int j2 = RES + 2 * b + jj;
#pragma unroll
                for (int r = 0; r < 4; r++) {
                    UH hv; hv.h = *(const half8*)&hh[r][j2 * 8];
#pragma unroll
                    for (int p = 0; p < 4; p++) {
                        a0[r] = __builtin_amdgcn_fdot2(hv.h2[p], sb[slot][jj][0].h2[p], a0[r], false);
                        a1[r] = __builtin_amdgcn_fdot2(hv.h2[p], sb[slot][jj][1].h2[p], a1[r], false);
                    }
                }
            }
            if (b + 3 < NSB) ISSUE(slot, b + 3);
        }
#undef ISSUE

        // ---- tanh + gate partials + wave reduce ----
        float o0[4], o1[4];
#pragma unroll
        for (int r = 0; r < 4; r++) { o0[r] = tanh_fast(a0[r]); o1[r] = tanh_fast(a1[r]); }

        float part[4][4];
#pragma unroll
        for (int r = 0; r < 4; r++)
#pragma unroll
            for (int kg = 0; kg < 4; kg++)
                part[r][kg] = fmaf(o0[r], Wg0[kg], o1[r] * Wg1[kg]);

#pragma unroll
        for (int m = 32; m > 0; m >>= 1) {
#pragma unroll
            for (int r = 0; r < 4; r++)
#pragma unroll
                for (int kg = 0; kg < 4; kg++)
                    part[r][kg] += __shfl_xor(part[r][kg], m, 64);
        }
        if (lane == 0) {
#pragma unroll
            for (int r = 0; r < 4; r++)
#pragma unroll
                for (int kg = 0; kg < 4; kg++)
                    red[wav][r * 4 + kg] = part[r][kg];
        }
        __syncthreads();   // red ready (hh reads of this step all done)

        // ---- softmax (redundant per thread, broadcast reads) ----
        float wA[4], wB[4];
#pragma unroll
        for (int r = 0; r < 4; r++) {
            float l0 = bg[0], l1 = bg[1], l2 = bg[2], l3 = bg[3];
#pragma unroll
            for (int w8 = 0; w8 < 8; w8++) {
                const float4 v = *(const float4*)&red[w8][r * 4];
                l0 += v.x; l1 += v.y; l2 += v.z; l3 += v.w;
            }
            const float mx = fmaxf(fmaxf(l0, l1), fmaxf(l2, l3));
            const float e0 = __expf(l0 - mx), e1 = __expf(l1 - mx);
            const float e2 = __expf(l2 - mx), e3 = __expf(l3 - mx);
            const float inv = __builtin_amdgcn_rcpf(e0 + e1 + e2 + e3);
            const float sm[4] = { e0 * inv, e1 * inv, e2 * inv, e3 * inv };
            wA[r] = sm[k0];          // weight for me0's compartment
            wB[r] = sm[k0 + 2];      // weight for me1's compartment
        }

        // ---- h_new partials ----
#pragma unroll
        for (int r = 0; r < 4; r++)
            hpart[k0][r][hp] = fmaf(wA[r], o0[r], wB[r] * o1[r]);
        __syncthreads();   // hpart ready

        // ---- combine h_new + stage x(t+1) ----
        if (tid < Hn) {
#pragma unroll
            for (int r = 0; r < 4; r++)
                hh[r][tid] = (_Float16)(hpart[0][r][tid] + hpart[1][r][tid]);
        } else if (is_x && (t + 1 < Tn)) {
            xs[xr][xi] = (_Float16)xpre;
        }
        // loop-top barrier orders hh/xs writes vs next step's reads
    }

    __syncthreads();
    // ---- final FC ----
    if (tid < 4 * On) {
        const int r = tid >> 4, o = tid & 15;
        float s = b_fc[o];
        for (int j = 0; j < Hn; j++)
            s = fmaf((float)hh[r][j], W_fc[o * Hn + j], s);
        out[(size_t)(b0 + r) * On + o] = s;
    }
}

extern "C" void kernel_launch(void* const* d_in, const int* in_sizes, int n_in,
                              void* d_out, int out_size, void* d_ws, size_t ws_size,
                              hipStream_t stream) {
    const float* x      = (const float*)d_in[0];
    const float* W_in   = (const float*)d_in[1];
    const float* b_in   = (const float*)d_in[2];
    const float* W_rec  = (const float*)d_in[3];
    const float* b_rec  = (const float*)d_in[4];
    const float* W_gate = (const float*)d_in[5];
    const float* b_gate = (const float*)d_in[6];
    const float* W_fc   = (const float*)d_in[7];
    const float* b_fc   = (const float*)d_in[8];
    float* out = (float*)d_out;

    _Float16* WPr = (_Float16*)d_ws;          // 32*1024*8 fp16 = 512 KB
    _Float16* WPi = WPr + 262144;             //  5*1024*8 fp16 =  80 KB

    pack_w<<<37, 1024, 0, stream>>>(W_rec, W_in, WPr, WPi);
    diru_reg<<<256, 512, 0, stream>>>(x, WPr, WPi, b_in, b_rec,
                                      W_gate, b_gate, W_fc, b_fc, out);
}

// Round 5
// 7254.482 us; speedup vs baseline: 1.2207x; 1.2207x over previous
//
#include <hip/hip_runtime.h>

#define Tn 512
#define In 40
#define Hn 256
#define Kn 4
#define On 16
#define RES 12              // resident rec j2-chunks per out-col (j < 96)
#define NJ2 32              // total rec j2-chunks (256/8)
#define NSB 10              // streamed batches (j2 pairs): j2 = 12..31

typedef _Float16 half8  __attribute__((ext_vector_type(8)));
typedef _Float16 half2v __attribute__((ext_vector_type(2)));

template<int P>
static __device__ __forceinline__ half2v h2c(half8 v) {
    return __builtin_shufflevector(v, v, 2 * P, 2 * P + 1);
}

static __device__ __forceinline__ half8 ld8(const _Float16* p) {
    return *(const half8*)p;
}

static __device__ __forceinline__ float tanh_fast(float x) {
    float e = __expf(2.f * x);
    return 1.f - 2.f * __builtin_amdgcn_rcpf(e + 1.f);
}

// acc += dot(hv, wv) over 8 fp16, via 4 fdot2 (all lane-static extracts)
#define D8(acc, hv, wv) do { \
    acc = __builtin_amdgcn_fdot2(h2c<0>(hv), h2c<0>(wv), acc, false); \
    acc = __builtin_amdgcn_fdot2(h2c<1>(hv), h2c<1>(wv), acc, false); \
    acc = __builtin_amdgcn_fdot2(h2c<2>(hv), h2c<2>(wv), acc, false); \
    acc = __builtin_amdgcn_fdot2(h2c<3>(hv), h2c<3>(wv), acc, false); } while (0)

// Pack weights to fp16, chunked for per-lane 16B loads:
//   WPr[(j2*1024 + me)*8 + j] = W_rec[me][j2*8+j],  j2 = 0..31, me = 0..1023
//   WPi[(i2*1024 + me)*8 + j] = W_in [me][i2*8+j],  i2 = 0..4   (40 = 5*8)
__global__ void pack_w(const float* __restrict__ Wr, const float* __restrict__ Wi,
                       _Float16* __restrict__ WPr, _Float16* __restrict__ WPi) {
    const int me = threadIdx.x;           // 0..1023
    const int c  = blockIdx.x;            // 0..36
    if (c < NJ2) {
#pragma unroll
        for (int j = 0; j < 8; j++)
            WPr[((size_t)c * 1024 + me) * 8 + j] = (_Float16)Wr[(size_t)me * Hn + c * 8 + j];
    } else {
        const int i2 = c - NJ2;
#pragma unroll
        for (int j = 0; j < 8; j++)
            WPi[((size_t)i2 * 1024 + me) * 8 + j] = (_Float16)Wi[(size_t)me * In + i2 * 8 + j];
    }
}

// 256 blocks x 512 threads (8 waves, 1 block/CU). Thread tid owns out-cols
// me0=tid, me1=tid+512 (same hp, compartments k0 and k0+2) for 4 batch rows.
// Rec weights j<96 + all input weights live in VGPRs (named half8, no unions
// -> SROA-promotable); j in [96,256) streamed from L2, 2-deep named buffers.
// h and x read from LDS at wave-uniform addresses (hardware broadcast).
__global__ __launch_bounds__(512, 2) void diru_reg(
    const float* __restrict__ x,
    const _Float16* __restrict__ WPr,
    const _Float16* __restrict__ WPi,
    const float* __restrict__ b_in, const float* __restrict__ b_rec,
    const float* __restrict__ W_gate, const float* __restrict__ b_gate,
    const float* __restrict__ W_fc, const float* __restrict__ b_fc,
    float* __restrict__ out)
{
    const int tid  = threadIdx.x;
    const int lane = tid & 63, wav = tid >> 6;
    const int me0  = tid, me1 = tid + 512;
    const int k0   = tid >> 8;            // 0 or 1 (me1 -> k0+2)
    const int hp   = tid & 255;
    const int b0   = blockIdx.x * 4;

    __shared__ _Float16 hh[4][Hn];        // carried h, fp16 (rows 512B)
    __shared__ _Float16 xs[4][In];        // x_t fp16 (rows 80B, 16B-aligned)
    __shared__ float    red[8][16];       // per-wave gate partials [wav][r*4+kg]
    __shared__ float    hpart[2][4][Hn];  // h_new partials by k0-half

    const half8* __restrict__ WR8 = (const half8*)WPr;
    const half8* __restrict__ WI8 = (const half8*)WPi;

    // ---- resident weights (statically-indexed half8 arrays) ----
    half8 wr0[RES], wr1[RES];
#pragma unroll
    for (int j2 = 0; j2 < RES; j2++) {
        wr0[j2] = WR8[(size_t)j2 * 1024 + me0];
        wr1[j2] = WR8[(size_t)j2 * 1024 + me1];
    }
    half8 wi0[5], wi1[5];
#pragma unroll
    for (int i2 = 0; i2 < 5; i2++) {
        wi0[i2] = WI8[(size_t)i2 * 1024 + me0];
        wi1[i2] = WI8[(size_t)i2 * 1024 + me1];
    }
    float Wg0[4], Wg1[4], bg[4];
#pragma unroll
    for (int kg = 0; kg < 4; kg++) {
        Wg0[kg] = W_gate[kg * 1024 + me0];
        Wg1[kg] = W_gate[kg * 1024 + me1];
        bg[kg]  = b_gate[kg];
    }
    const float bias0 = b_in[me0] + b_rec[me0];
    const float bias1 = b_in[me1] + b_rec[me1];

    // ---- init LDS: zero h, stage x(t=0) ----
    for (int i = tid; i < 4 * Hn; i += 512) ((_Float16*)hh)[i] = (_Float16)0.f;
    const int  xv_id  = tid - 256;                       // threads 256..415 stage x
    const bool is_x   = (xv_id >= 0) && (xv_id < 4 * In);
    const int  xr     = is_x ? (xv_id / In) : 0;
    const int  xi     = is_x ? (xv_id - xr * In) : 0;
    const float* xp   = x + ((size_t)(b0 + xr) * Tn) * In + xi;
    if (is_x) xs[xr][xi] = (_Float16)xp[0];

#define ISSUE_A(b) { \
    sbA0 = WR8[(size_t)((RES + 2*(b))     * 1024) + me0]; \
    sbA1 = WR8[(size_t)((RES + 2*(b) + 1) * 1024) + me0]; \
    sbA2 = WR8[(size_t)((RES + 2*(b))     * 1024) + me1]; \
    sbA3 = WR8[(size_t)((RES + 2*(b) + 1) * 1024) + me1]; }
#define ISSUE_B(b) { \
    sbB0 = WR8[(size_t)((RES + 2*(b))     * 1024) + me0]; \
    sbB1 = WR8[(size_t)((RES + 2*(b) + 1) * 1024) + me0]; \
    sbB2 = WR8[(size_t)((RES + 2*(b))     * 1024) + me1]; \
    sbB3 = WR8[(size_t)((RES + 2*(b) + 1) * 1024) + me1]; }
#define CONSUME(j2c, W0, W1) { \
    _Pragma("unroll") \
    for (int r = 0; r < 4; r++) { \
        const half8 hv = ld8(&hh[r][(j2c) * 8]); \
        D8(a0[r], hv, W0); \
        D8(a1[r], hv, W1); } }

    for (int t = 0; t < Tn; t++) {
        // prefetch next x early (lands during compute)
        float xpre = 0.f;
        if (is_x && (t + 1 < Tn)) xpre = xp[(size_t)(t + 1) * In];

        __syncthreads();   // hh(t), xs(t) ready

        float a0[4], a1[4];
#pragma unroll
        for (int r = 0; r < 4; r++) { a0[r] = bias0; a1[r] = bias1; }

        half8 sbA0, sbA1, sbA2, sbA3, sbB0, sbB1, sbB2, sbB3;

        // ---- input projection (broadcast xs reads, resident weights) ----
#pragma unroll
        for (int i2 = 0; i2 < 5; i2++) {
#pragma unroll
            for (int r = 0; r < 4; r++) {
                const half8 xv = ld8(&xs[r][i2 * 8]);
                D8(a0[r], xv, wi0[i2]);
                D8(a1[r], xv, wi1[i2]);
            }
        }

        // ---- recurrent, resident half (j < 96), stream issues interleaved ----
#pragma unroll
        for (int j2 = 0; j2 < RES; j2++) {
            if (j2 == 4) ISSUE_A(0);
            if (j2 == 8) ISSUE_B(1);
            CONSUME(j2, wr0[j2], wr1[j2]);
        }

        // ---- recurrent, streamed half (j in [96,256)), 2-deep pipeline ----
#pragma unroll
        for (int b = 0; b < NSB; b += 2) {
            CONSUME(RES + 2 * b,     sbA0, sbA2);
            CONSUME(RES + 2 * b + 1, sbA1, sbA3);
            if (b + 2 < NSB) ISSUE_A(b + 2);
            CONSUME(RES + 2 * b + 2, sbB0, sbB2);
            CONSUME(RES + 2 * b + 3, sbB1, sbB3);
            if (b + 3 < NSB) ISSUE_B(b + 3);
        }

        // ---- tanh + gate partials + wave butterfly reduce ----
        float o0[4], o1[4];
#pragma unroll
        for (int r = 0; r < 4; r++) { o0[r] = tanh_fast(a0[r]); o1[r] = tanh_fast(a1[r]); }

        float part[4][4];
#pragma unroll
        for (int r = 0; r < 4; r++)
#pragma unroll
            for (int kg = 0; kg < 4; kg++)
                part[r][kg] = fmaf(o0[r], Wg0[kg], o1[r] * Wg1[kg]);

#pragma unroll
        for (int m = 32; m > 0; m >>= 1) {
#pragma unroll
            for (int r = 0; r < 4; r++)
#pragma unroll
                for (int kg = 0; kg < 4; kg++)
                    part[r][kg] += __shfl_xor(part[r][kg], m, 64);
        }
        if (lane == 0) {
#pragma unroll
            for (int r = 0; r < 4; r++)
#pragma unroll
                for (int kg = 0; kg < 4; kg++)
                    red[wav][r * 4 + kg] = part[r][kg];
        }
        __syncthreads();   // red ready (hh reads of this step all done)

        // ---- softmax (redundant per thread, broadcast reads) ----
        float wA[4], wB[4];
#pragma unroll
        for (int r = 0; r < 4; r++) {
            float l0 = bg[0], l1 = bg[1], l2 = bg[2], l3 = bg[3];
#pragma unroll
            for (int w8 = 0; w8 < 8; w8++) {
                const float4 v = *(const float4*)&red[w8][r * 4];
                l0 += v.x; l1 += v.y; l2 += v.z; l3 += v.w;
            }
            const float mx = fmaxf(fmaxf(l0, l1), fmaxf(l2, l3));
            const float e0 = __expf(l0 - mx), e1 = __expf(l1 - mx);
            const float e2 = __expf(l2 - mx), e3 = __expf(l3 - mx);
            const float inv = __builtin_amdgcn_rcpf(e0 + e1 + e2 + e3);
            const float s0 = e0 * inv, s1 = e1 * inv, s2 = e2 * inv, s3 = e3 * inv;
            wA[r] = (k0 == 0) ? s0 : s1;     // compartment of me0
            wB[r] = (k0 == 0) ? s2 : s3;     // compartment of me1
        }

        // ---- h_new partials ----
#pragma unroll
        for (int r = 0; r < 4; r++)
            hpart[k0][r][hp] = fmaf(wA[r], o0[r], wB[r] * o1[r]);
        __syncthreads();   // hpart ready

        // ---- combine h_new + stage x(t+1) ----
        if (tid < Hn) {
#pragma unroll
            for (int r = 0; r < 4; r++)
                hh[r][tid] = (_Float16)(hpart[0][r][tid] + hpart[1][r][tid]);
        } else if (is_x && (t + 1 < Tn)) {
            xs[xr][xi] = (_Float16)xpre;
        }
        // loop-top barrier orders hh/xs writes vs next step's reads
    }

    __syncthreads();
    // ---- final FC ----
    if (tid < 4 * On) {
        const int r = tid >> 4, o = tid & 15;
        float s = b_fc[o];
        for (int j = 0; j < Hn; j++)
            s = fmaf((float)hh[r][j], W_fc[o * Hn + j], s);
        out[(size_t)(b0 + r) * On + o] = s;
    }
#undef ISSUE_A
#undef ISSUE_B
#undef CONSUME
}

extern "C" void kernel_launch(void* const* d_in, const int* in_sizes, int n_in,
                              void* d_out, int out_size, void* d_ws, size_t ws_size,
                              hipStream_t stream) {
    const float* x      = (const float*)d_in[0];
    const float* W_in   = (const float*)d_in[1];
    const float* b_in   = (const float*)d_in[2];
    const float* W_rec  = (const float*)d_in[3];
    const float* b_rec  = (const float*)d_in[4];
    const float* W_gate = (const float*)d_in[5];
    const float* b_gate = (const float*)d_in[6];
    const float* W_fc   = (const float*)d_in[7];
    const float* b_fc   = (const float*)d_in[8];
    float* out = (float*)d_out;

    _Float16* WPr = (_Float16*)d_ws;          // 32*1024*8 fp16 = 512 KB
    _Float16* WPi = WPr + 262144;             //  5*1024*8 fp16 =  80 KB

    pack_w<<<37, 1024, 0, stream>>>(W_rec, W_in, WPr, WPi);
    diru_reg<<<256, 512, 0, stream>>>(x, WPr, WPi, b_in, b_rec,
                                      W_gate, b_gate, W_fc, b_fc, out);
}